// Round 5
// baseline (641.096 us; speedup 1.0000x reference)
//
#include <hip/hip_runtime.h>

#define BB 16
#define NN 256
#define DD 64
#define EE 64
#define HH 8

typedef __attribute__((ext_vector_type(4))) float f32x4;
typedef __attribute__((ext_vector_type(8))) short short8;

__device__ __forceinline__ void fma4(float* acc, float x, float4 w) {
    acc[0] += x * w.x; acc[1] += x * w.y; acc[2] += x * w.z; acc[3] += x * w.w;
}

// fp32 -> bf16 round-to-nearest-even
__device__ __forceinline__ unsigned short f2bf(float f) {
    union { float f; unsigned u; } v; v.f = f;
    unsigned r = v.u + 0x7FFFu + ((v.u >> 16) & 1u);
    return (unsigned short)(r >> 16);
}

// ---------------------------------------------------------------------------
// Kernel 1: QKV projection (fp32 compute), bf16 outputs:
//   Qb [b,h,n,d] (pre-scaled by 0.125), Kb [b,h,n,d], Vtb [b,h,d,n] (transposed).
// grid 1536 (mtx x b x n-tile-of-8), 256 threads.
// ---------------------------------------------------------------------------
__global__ __launch_bounds__(256) void qkv_kernel(
    const float* __restrict__ query,
    const float* __restrict__ Wq, const float* __restrict__ bq,
    const float* __restrict__ Wk, const float* __restrict__ bk,
    const float* __restrict__ Wv, const float* __restrict__ bv,
    unsigned short* __restrict__ Qb, unsigned short* __restrict__ Kb,
    unsigned short* __restrict__ Vtb)
{
    __shared__ __align__(16) float q_l[8][64];
    const int mtx = blockIdx.x >> 9;          // 0:Q 1:K 2:V
    const int rem = blockIdx.x & 511;
    const int b   = rem >> 5;
    const int n0  = (rem & 31) << 3;
    const int tid = threadIdx.x;

    if (tid < 128)
        ((float4*)&q_l[0][0])[tid] =
            ((const float4*)(query + (size_t)(b * NN + n0) * DD))[tid];

    const int w    = tid >> 6;                // wave -> rows 2w, 2w+1
    const int lane = tid & 63;
    const int r0   = w * 2;
    const float* W  = (mtx == 0) ? Wq : (mtx == 1) ? Wk : Wv;
    const float* bs = (mtx == 0) ? bq : (mtx == 1) ? bk : bv;

    const int c0 = lane << 2;
    float acc[2][2][4];
    {
        const float4 b0 = *(const float4*)(bs + c0);
        const float4 b1 = *(const float4*)(bs + 256 + c0);
        acc[0][0][0]=b0.x; acc[0][0][1]=b0.y; acc[0][0][2]=b0.z; acc[0][0][3]=b0.w;
        acc[0][1][0]=b1.x; acc[0][1][1]=b1.y; acc[0][1][2]=b1.z; acc[0][1][3]=b1.w;
        acc[1][0][0]=b0.x; acc[1][0][1]=b0.y; acc[1][0][2]=b0.z; acc[1][0][3]=b0.w;
        acc[1][1][0]=b1.x; acc[1][1][1]=b1.y; acc[1][1][2]=b1.z; acc[1][1][3]=b1.w;
    }
    __syncthreads();

    #pragma unroll 2
    for (int d4 = 0; d4 < 16; ++d4) {
        const float4 qa = ((const float4*)&q_l[r0][0])[d4];
        const float4 qb = ((const float4*)&q_l[r0 + 1][0])[d4];
        const float qav[4] = {qa.x, qa.y, qa.z, qa.w};
        const float qbv[4] = {qb.x, qb.y, qb.z, qb.w};
        #pragma unroll
        for (int k = 0; k < 4; ++k) {
            const float4 w0 = *(const float4*)(W + (size_t)(d4 * 4 + k) * 512 + c0);
            const float4 w1 = *(const float4*)(W + (size_t)(d4 * 4 + k) * 512 + 256 + c0);
            fma4(acc[0][0], qav[k], w0); fma4(acc[0][1], qav[k], w1);
            fma4(acc[1][0], qbv[k], w0); fma4(acc[1][1], qbv[k], w1);
        }
    }

    const int hq = lane >> 4;                 // h within j-half
    const int d0 = (lane & 15) << 2;
    if (mtx < 2) {
        unsigned short* T = (mtx == 0) ? Qb : Kb;
        const float scale = (mtx == 0) ? 0.125f : 1.0f;
        #pragma unroll
        for (int r = 0; r < 2; ++r)
            #pragma unroll
            for (int j = 0; j < 2; ++j) {
                const int h = j * 4 + hq;
                const unsigned int lo = (unsigned)f2bf(acc[r][j][0] * scale)
                                      | ((unsigned)f2bf(acc[r][j][1] * scale) << 16);
                const unsigned int hi = (unsigned)f2bf(acc[r][j][2] * scale)
                                      | ((unsigned)f2bf(acc[r][j][3] * scale) << 16);
                uint2* p = (uint2*)(T + ((size_t)(b * HH + h) * NN + n0 + r0 + r) * DD + d0);
                *p = make_uint2(lo, hi);
            }
    } else {
        #pragma unroll
        for (int r = 0; r < 2; ++r)
            #pragma unroll
            for (int j = 0; j < 2; ++j) {
                const int h = j * 4 + hq;
                #pragma unroll
                for (int k = 0; k < 4; ++k)
                    Vtb[((size_t)(b * HH + h) * DD + d0 + k) * NN + n0 + r0 + r] =
                        f2bf(acc[r][j][k]);
            }
    }
}

// ---------------------------------------------------------------------------
// Kernel 2: fused edges pass with IN-KERNEL QK^T (qk_kernel deleted).
//   block = (b, n, m-half of 128), grid 8192, 256 threads.
//   - edges tile [128m][64e] staged coalesced fp32->bf16 LDS (XOR swizzle)
//   - qk[8h][128m] via MFMA: A = replicated Q row (direct short8 loads),
//     B = K rows (direct short8 loads, L2-resident 128 KB tile) -> qk_l LDS
//   - MLP = MFMA [128,64]@[64,16] (Wa|Wg) -> bgl
//   - fixup: sc = qk_l + bias + ba; coalesced scores/gates writes
//   - phase 2: edges_out from sc (LDS broadcasts), NT stores
// LDS ~31.4 KB -> 5 blocks/CU.
// ---------------------------------------------------------------------------
__global__ __launch_bounds__(256) void edges_kernel(
    const float* __restrict__ edges,
    const unsigned short* __restrict__ Qb, const unsigned short* __restrict__ Kb,
    const float* __restrict__ Wa, const float* __restrict__ ba,
    const float* __restrict__ Wg, const float* __restrict__ bg,
    const float* __restrict__ We, const float* __restrict__ be,
    float* __restrict__ scores,
    unsigned short* __restrict__ gates,
    float* __restrict__ edges_out)
{
    __shared__ __align__(16) unsigned short eb[128 * 64];   // 16 KB, swizzled
    __shared__ __align__(16) unsigned short wc[16 * 64];    //  2 KB, WcatT[h'][e]
    __shared__ float bgl[128][17];                          // 8.7 KB (odd stride)
    __shared__ float qk_l[8][132];                          // 4.2 KB
    __shared__ float bal[8], bgb[8];

    const int mh  = blockIdx.x & 1;
    const int n   = (blockIdx.x >> 1) & 255;
    const int b   = blockIdx.x >> 9;
    const int m0  = mh << 7;
    const int tid = threadIdx.x;
    const int w   = tid >> 6, l = tid & 63;
    const int lr  = l & 15, lg = l >> 4;

    // phase-2 constants
    float wecol[8];
    #pragma unroll
    for (int h = 0; h < 8; ++h) wecol[h] = We[h * EE + l];
    const float bev = be[l];

    // --- issue edges tile loads (NT, coalesced) into registers
    const f32x4* esrc = (const f32x4*)(edges + ((size_t)(b * NN + n) * NN + m0) * DD);
    f32x4 xr[8];
    #pragma unroll
    for (int it = 0; it < 8; ++it)
        xr[it] = __builtin_nontemporal_load(esrc + it * 256 + tid);

    // --- in-kernel QK^T: wave w computes h = {2w, 2w+1}
    //     A-frag = Q row n (replicated across rows), B-frag = K rows m.
    #pragma unroll
    for (int hh = 0; hh < 2; ++hh) {
        const int h = w * 2 + hh;
        const unsigned short* qp = Qb + ((size_t)(b * HH + h) * NN + n) * DD + lg * 8;
        const short8 qf0 = *(const short8*)qp;
        const short8 qf1 = *(const short8*)(qp + 32);
        const unsigned short* kp = Kb + ((size_t)(b * HH + h) * NN + m0 + lr) * DD + lg * 8;
        #pragma unroll
        for (int T = 0; T < 8; ++T) {
            const short8 k0 = *(const short8*)(kp + (size_t)T * 16 * DD);
            const short8 k1 = *(const short8*)(kp + (size_t)T * 16 * DD + 32);
            f32x4 a = (f32x4){0.f, 0.f, 0.f, 0.f};
            a = __builtin_amdgcn_mfma_f32_16x16x32_bf16(qf0, k0, a, 0, 0, 0);
            a = __builtin_amdgcn_mfma_f32_16x16x32_bf16(qf1, k1, a, 0, 0, 0);
            if (lg == 0) qk_l[h][T * 16 + lr] = a[0];   // rows replicated; take row 0
        }
    }

    // --- stage WcatT[h'][e] bf16 (h'<8 -> Wa, else Wg), swizzled
    #pragma unroll
    for (int j = 0; j < 4; ++j) {
        const int idx = tid * 4 + j;
        const int hp = idx >> 6, e = idx & 63;
        const float v = (hp < 8) ? Wa[e * 8 + hp] : Wg[e * 8 + (hp - 8)];
        *(unsigned short*)((char*)wc + hp * 128 + ((e * 2) ^ ((hp & 7) << 4))) = f2bf(v);
    }
    if (tid < 8) { bal[tid] = ba[tid]; bgb[tid] = bg[tid]; }

    // --- write edges tile to LDS (bf16, swizzled)
    #pragma unroll
    for (int it = 0; it < 8; ++it) {
        const int c = it * 256 + tid;            // float4 index: m = c>>4, e4 = c&15
        const int m = c >> 4, e4 = c & 15;
        const unsigned lo = (unsigned)f2bf(xr[it][0]) | ((unsigned)f2bf(xr[it][1]) << 16);
        const unsigned hi = (unsigned)f2bf(xr[it][2]) | ((unsigned)f2bf(xr[it][3]) << 16);
        *(uint2*)((char*)eb + m * 128 + ((e4 * 8) ^ ((m & 7) << 4))) = make_uint2(lo, hi);
    }
    __syncthreads();

    // --- B fragments (WcatT rows, conflict-free via swizzle)
    short8 bfrag[2];
    #pragma unroll
    for (int ks = 0; ks < 2; ++ks)
        bfrag[ks] = *(const short8*)((char*)wc + lr * 128 +
                                     ((ks * 64 + lg * 16) ^ ((lr & 7) << 4)));

    // --- MFMA MLP: wave w owns m-tiles {2w, 2w+1}
    #pragma unroll
    for (int t = 0; t < 2; ++t) {
        const int T = w * 2 + t;
        f32x4 acc = (f32x4){0.f, 0.f, 0.f, 0.f};
        #pragma unroll
        for (int ks = 0; ks < 2; ++ks) {
            const int m = T * 16 + lr;
            const short8 af = *(const short8*)((char*)eb + m * 128 +
                                 ((ks * 64 + lg * 16) ^ ((lr & 7) << 4)));
            acc = __builtin_amdgcn_mfma_f32_16x16x32_bf16(af, bfrag[ks], acc, 0, 0, 0);
        }
        // C: col (h') = lr, row (m-in-tile) = lg*4 + r
        #pragma unroll
        for (int r = 0; r < 4; ++r)
            bgl[T * 16 + lg * 4 + r][lr] = acc[r];
    }
    __syncthreads();

    // --- fixup: thread = (hgroup = tid>>7, m = tid&127); all LDS sources
    {
        const int fm = tid & 127;
        const int fh = (tid >> 7) << 2;
        const size_t so0 = ((size_t)(b * HH + fh) << 16) + ((size_t)n << 8) + m0 + fm;
        float qk4[4];
        #pragma unroll
        for (int i = 0; i < 4; ++i) qk4[i] = qk_l[fh + i][fm];
        #pragma unroll
        for (int i = 0; i < 4; ++i) {
            const int h = fh + i;
            const float sc = qk4[i] + bgl[fm][h] + bal[h];
            scores[so0 + ((size_t)i << 16)] = sc;
            bgl[fm][h] = sc;                      // slot owned by this thread
            const float gv = bgl[fm][8 + h] + bgb[h];
            gates[so0 + ((size_t)i << 16)] = f2bf(1.f / (1.f + __expf(-gv)));
        }
    }
    __syncthreads();

    // --- phase 2: edges_out[b, m, n, e] = sum_h sc[m][h] * We[h][e] + be[e]
    #pragma unroll 4
    for (int mi = 0; mi < 32; ++mi) {
        const int m = w * 32 + mi;
        float v = bev;
        #pragma unroll
        for (int h = 0; h < 8; ++h) v += bgl[m][h] * wecol[h];   // LDS broadcast
        __builtin_nontemporal_store(v,
            edges_out + ((size_t)(b * NN + m0 + m) * NN + n) * DD + l);
    }
}

// ---------------------------------------------------------------------------
// Kernel 3: Vgt[b,h,d,n] = (V^T @ g^T) via bf16 MFMA.
// grid 1024 (bh x 4 n-quarters x 2 d-halves), 256 threads, no LDS.
// ---------------------------------------------------------------------------
__global__ __launch_bounds__(256) void vg_kernel(
    const unsigned short* __restrict__ gates, const unsigned short* __restrict__ Vtb,
    unsigned short* __restrict__ Vgt)
{
    const int dh = blockIdx.x & 1;
    const int q  = (blockIdx.x >> 1) & 3;
    const int bh = blockIdx.x >> 3;
    const int tid = threadIdx.x;
    const int w = tid >> 6, l = tid & 63;
    const int lr = l & 15, lg = l >> 4;
    const int n0 = q * 64 + w * 16;

    const unsigned short* gp = gates + ((size_t)bh * NN + n0 + lr) * NN + lg * 8;
    const unsigned short* vp = Vtb + ((size_t)bh * DD + lr) * NN + lg * 8;

    f32x4 acc[2];
    #pragma unroll
    for (int dt = 0; dt < 2; ++dt) acc[dt] = (f32x4){0.f, 0.f, 0.f, 0.f};

    #pragma unroll
    for (int ks = 0; ks < 8; ++ks) {
        const short8 bfr = *(const short8*)(gp + ks * 32);
        #pragma unroll
        for (int dt = 0; dt < 2; ++dt) {
            const short8 afr = *(const short8*)(vp + (size_t)(dh * 2 + dt) * 16 * NN + ks * 32);
            acc[dt] = __builtin_amdgcn_mfma_f32_16x16x32_bf16(afr, bfr, acc[dt], 0, 0, 0);
        }
    }

    unsigned short* op = Vgt + (size_t)bh * DD * NN;
    #pragma unroll
    for (int dt = 0; dt < 2; ++dt)
        #pragma unroll
        for (int r = 0; r < 4; ++r)
            op[(size_t)((dh * 2 + dt) * 16 + lg * 4 + r) * NN + n0 + lr] = f2bf(acc[dt][r]);
}

// ---------------------------------------------------------------------------
// Kernel 4: softmax(scores) @ Vg + projection. 512 threads, wave = head.
// grid 256 (b x 16 n-tiles), LDS 33.3 KB. NT scores reads (last consumer).
// ---------------------------------------------------------------------------
__global__ __launch_bounds__(512) void out_kernel(
    const float* __restrict__ scores, const unsigned short* __restrict__ Vgt,
    const float* __restrict__ Wo, const float* __restrict__ bo,
    float* __restrict__ att_out)
{
    __shared__ float o_l[16][521];
    const int b  = blockIdx.x >> 4;
    const int nt = blockIdx.x & 15;
    const int n0 = nt * 16;
    const int tid = threadIdx.x;
    const int w = tid >> 6, l = tid & 63;
    const int lr = l & 15, lg = l >> 4;
    const int h = w;                          // one head per wave

    {
        const f32x4* sp = (const f32x4*)(scores +
            ((size_t)(b * HH + h) * NN + n0 + lr) * NN + lg * 8);
        float s[64];
        #pragma unroll
        for (int ks = 0; ks < 8; ++ks) {
            const f32x4 x0 = __builtin_nontemporal_load(sp + ks * 8);
            const f32x4 x1 = __builtin_nontemporal_load(sp + ks * 8 + 1);
            s[ks * 8 + 0] = x0[0]; s[ks * 8 + 1] = x0[1];
            s[ks * 8 + 2] = x0[2]; s[ks * 8 + 3] = x0[3];
            s[ks * 8 + 4] = x1[0]; s[ks * 8 + 5] = x1[1];
            s[ks * 8 + 6] = x1[2]; s[ks * 8 + 7] = x1[3];
        }
        float mx = -1e30f;
        #pragma unroll
        for (int i = 0; i < 64; ++i) mx = fmaxf(mx, s[i]);
        mx = fmaxf(mx, __shfl_xor(mx, 16, 64));
        mx = fmaxf(mx, __shfl_xor(mx, 32, 64));
        float sm = 0.f;
        #pragma unroll
        for (int i = 0; i < 64; ++i) { s[i] = __expf(s[i] - mx); sm += s[i]; }
        sm += __shfl_xor(sm, 16, 64);
        sm += __shfl_xor(sm, 32, 64);
        const float inv = 1.f / sm;

        const unsigned short* vp = Vgt + ((size_t)(b * HH + h) * DD + lr) * NN + lg * 8;
        f32x4 acc[4];
        #pragma unroll
        for (int dt = 0; dt < 4; ++dt) acc[dt] = (f32x4){0.f, 0.f, 0.f, 0.f};

        #pragma unroll
        for (int ks = 0; ks < 8; ++ks) {
            union { short8 v; unsigned short u[8]; } bf;
            #pragma unroll
            for (int j = 0; j < 8; ++j) bf.u[j] = f2bf(s[ks * 8 + j] * inv);
            #pragma unroll
            for (int dt = 0; dt < 4; ++dt) {
                const short8 afr = *(const short8*)(vp + (size_t)dt * 16 * NN + ks * 32);
                acc[dt] = __builtin_amdgcn_mfma_f32_16x16x32_bf16(afr, bf.v, acc[dt], 0, 0, 0);
            }
        }
        // C: row = d' = dt*16+lg*4+r, col = n' = lr
        #pragma unroll
        for (int dt = 0; dt < 4; ++dt)
            #pragma unroll
            for (int r = 0; r < 4; ++r)
                o_l[lr][h * 64 + dt * 16 + lg * 4 + r] = acc[dt][r];
    }
    __syncthreads();

    // projection: thread (n = tid>>5, d-pair = (tid&31)*2); Wo coalesced
    const int n  = tid >> 5;
    const int d2 = (tid & 31) << 1;
    float a0 = bo[d2], a1 = bo[d2 + 1];
    const float* orow = &o_l[n][0];
    #pragma unroll 8
    for (int k = 0; k < 512; ++k) {
        const float o = orow[k];
        const float2 w2 = *(const float2*)(Wo + (size_t)k * 64 + d2);
        a0 += o * w2.x; a1 += o * w2.y;
    }
    *(float2*)(att_out + ((size_t)(b * NN + n0 + n)) * DD + d2) = make_float2(a0, a1);
}

extern "C" void kernel_launch(void* const* d_in, const int* in_sizes, int n_in,
                              void* d_out, int out_size, void* d_ws, size_t ws_size,
                              hipStream_t stream)
{
    const float* query = (const float*)d_in[0];
    const float* edges = (const float*)d_in[1];
    const float* Wq = (const float*)d_in[2];  const float* bq = (const float*)d_in[3];
    const float* Wk = (const float*)d_in[4];  const float* bk = (const float*)d_in[5];
    const float* Wv = (const float*)d_in[6];  const float* bv = (const float*)d_in[7];
    const float* Wa = (const float*)d_in[8];  const float* ba = (const float*)d_in[9];
    const float* Wg = (const float*)d_in[10]; const float* bg = (const float*)d_in[11];
    const float* Wo = (const float*)d_in[12]; const float* bo = (const float*)d_in[13];
    const float* We = (const float*)d_in[14]; const float* be = (const float*)d_in[15];

    float* att_out   = (float*)d_out;
    float* edges_out = (float*)d_out + 262144;  // B*N*D

    char* base = (char*)d_ws;
    float*          scores = (float*)base;                          // 33,554,432 B
    unsigned short* gates  = (unsigned short*)(base + 33554432);    // 16,777,216 B
    unsigned short* Qb     = (unsigned short*)(base + 50331648);    //  4,194,304 B
    unsigned short* Kb     = (unsigned short*)(base + 54525952);    //  4,194,304 B
    unsigned short* Vtb    = (unsigned short*)(base + 58720256);    //  4,194,304 B
    unsigned short* Vgt    = (unsigned short*)(base + 62914560);    //  4,194,304 B

    hipLaunchKernelGGL(qkv_kernel, dim3(1536), dim3(256), 0, stream,
                       query, Wq, bq, Wk, bk, Wv, bv, Qb, Kb, Vtb);
    hipLaunchKernelGGL(edges_kernel, dim3(8192), dim3(256), 0, stream,
                       edges, Qb, Kb, Wa, ba, Wg, bg, We, be, scores, gates, edges_out);
    hipLaunchKernelGGL(vg_kernel, dim3(1024), dim3(256), 0, stream,
                       gates, Vtb, Vgt);
    hipLaunchKernelGGL(out_kernel, dim3(256), dim3(512), 0, stream,
                       scores, Vgt, Wo, bo, att_out);
}

// Round 6
// 574.967 us; speedup vs baseline: 1.1150x; 1.1150x over previous
//
#include <hip/hip_runtime.h>

#define BB 16
#define NN 256
#define DD 64
#define EE 64
#define HH 8

typedef __attribute__((ext_vector_type(4))) float f32x4;
typedef __attribute__((ext_vector_type(8))) short short8;

__device__ __forceinline__ void fma4(float* acc, float x, float4 w) {
    acc[0] += x * w.x; acc[1] += x * w.y; acc[2] += x * w.z; acc[3] += x * w.w;
}

// fp32 -> bf16 round-to-nearest-even
__device__ __forceinline__ unsigned short f2bf(float f) {
    union { float f; unsigned u; } v; v.f = f;
    unsigned r = v.u + 0x7FFFu + ((v.u >> 16) & 1u);
    return (unsigned short)(r >> 16);
}

// ---------------------------------------------------------------------------
// Kernel 1: QKV projection (fp32 compute), bf16 outputs:
//   Qb [b,h,n,d] (pre-scaled by 0.125), Kb [b,h,n,d], Vtb [b,h,d,n] (transposed).
// grid 1536 (mtx x b x n-tile-of-8), 256 threads.
// ---------------------------------------------------------------------------
__global__ __launch_bounds__(256) void qkv_kernel(
    const float* __restrict__ query,
    const float* __restrict__ Wq, const float* __restrict__ bq,
    const float* __restrict__ Wk, const float* __restrict__ bk,
    const float* __restrict__ Wv, const float* __restrict__ bv,
    unsigned short* __restrict__ Qb, unsigned short* __restrict__ Kb,
    unsigned short* __restrict__ Vtb)
{
    __shared__ __align__(16) float q_l[8][64];
    const int mtx = blockIdx.x >> 9;          // 0:Q 1:K 2:V
    const int rem = blockIdx.x & 511;
    const int b   = rem >> 5;
    const int n0  = (rem & 31) << 3;
    const int tid = threadIdx.x;

    if (tid < 128)
        ((float4*)&q_l[0][0])[tid] =
            ((const float4*)(query + (size_t)(b * NN + n0) * DD))[tid];

    const int w    = tid >> 6;                // wave -> rows 2w, 2w+1
    const int lane = tid & 63;
    const int r0   = w * 2;
    const float* W  = (mtx == 0) ? Wq : (mtx == 1) ? Wk : Wv;
    const float* bs = (mtx == 0) ? bq : (mtx == 1) ? bk : bv;

    const int c0 = lane << 2;
    float acc[2][2][4];
    {
        const float4 b0 = *(const float4*)(bs + c0);
        const float4 b1 = *(const float4*)(bs + 256 + c0);
        acc[0][0][0]=b0.x; acc[0][0][1]=b0.y; acc[0][0][2]=b0.z; acc[0][0][3]=b0.w;
        acc[0][1][0]=b1.x; acc[0][1][1]=b1.y; acc[0][1][2]=b1.z; acc[0][1][3]=b1.w;
        acc[1][0][0]=b0.x; acc[1][0][1]=b0.y; acc[1][0][2]=b0.z; acc[1][0][3]=b0.w;
        acc[1][1][0]=b1.x; acc[1][1][1]=b1.y; acc[1][1][2]=b1.z; acc[1][1][3]=b1.w;
    }
    __syncthreads();

    #pragma unroll 2
    for (int d4 = 0; d4 < 16; ++d4) {
        const float4 qa = ((const float4*)&q_l[r0][0])[d4];
        const float4 qb = ((const float4*)&q_l[r0 + 1][0])[d4];
        const float qav[4] = {qa.x, qa.y, qa.z, qa.w};
        const float qbv[4] = {qb.x, qb.y, qb.z, qb.w};
        #pragma unroll
        for (int k = 0; k < 4; ++k) {
            const float4 w0 = *(const float4*)(W + (size_t)(d4 * 4 + k) * 512 + c0);
            const float4 w1 = *(const float4*)(W + (size_t)(d4 * 4 + k) * 512 + 256 + c0);
            fma4(acc[0][0], qav[k], w0); fma4(acc[0][1], qav[k], w1);
            fma4(acc[1][0], qbv[k], w0); fma4(acc[1][1], qbv[k], w1);
        }
    }

    const int hq = lane >> 4;                 // h within j-half
    const int d0 = (lane & 15) << 2;
    if (mtx < 2) {
        unsigned short* T = (mtx == 0) ? Qb : Kb;
        const float scale = (mtx == 0) ? 0.125f : 1.0f;
        #pragma unroll
        for (int r = 0; r < 2; ++r)
            #pragma unroll
            for (int j = 0; j < 2; ++j) {
                const int h = j * 4 + hq;
                const unsigned int lo = (unsigned)f2bf(acc[r][j][0] * scale)
                                      | ((unsigned)f2bf(acc[r][j][1] * scale) << 16);
                const unsigned int hi = (unsigned)f2bf(acc[r][j][2] * scale)
                                      | ((unsigned)f2bf(acc[r][j][3] * scale) << 16);
                uint2* p = (uint2*)(T + ((size_t)(b * HH + h) * NN + n0 + r0 + r) * DD + d0);
                *p = make_uint2(lo, hi);
            }
    } else {
        #pragma unroll
        for (int r = 0; r < 2; ++r)
            #pragma unroll
            for (int j = 0; j < 2; ++j) {
                const int h = j * 4 + hq;
                #pragma unroll
                for (int k = 0; k < 4; ++k)
                    Vtb[((size_t)(b * HH + h) * DD + d0 + k) * NN + n0 + r0 + r] =
                        f2bf(acc[r][j][k]);
            }
    }
}

// ---------------------------------------------------------------------------
// Kernel 2: scores = (Q @ K^T)/8 via bf16 MFMA (scale folded into Qb).
// grid 1024 (bh x 4 n-tiles-of-64 x 2 m-halves-of-128), 256 thr, no LDS.
// ---------------------------------------------------------------------------
__global__ __launch_bounds__(256) void qk_kernel(
    const unsigned short* __restrict__ Qb, const unsigned short* __restrict__ Kb,
    float* __restrict__ scores)
{
    const int bh = blockIdx.x >> 3;
    const int nt = (blockIdx.x >> 1) & 3;
    const int mh = blockIdx.x & 1;
    const int tid = threadIdx.x;
    const int w = tid >> 6, l = tid & 63;
    const int lr = l & 15, lg = l >> 4;
    const int n0 = nt * 64 + w * 16;

    const unsigned short* qp = Qb + ((size_t)bh * NN + n0 + lr) * DD + lg * 8;
    const unsigned short* kp = Kb + ((size_t)bh * NN + mh * 128 + lr) * DD + lg * 8;

    const short8 a0 = *(const short8*)qp;
    const short8 a1 = *(const short8*)(qp + 32);

    f32x4 acc[8];
    #pragma unroll
    for (int mt = 0; mt < 8; ++mt) acc[mt] = (f32x4){0.f, 0.f, 0.f, 0.f};

    #pragma unroll
    for (int mt = 0; mt < 8; ++mt) {
        const short8 b0 = *(const short8*)(kp + (size_t)mt * 16 * DD);
        const short8 b1 = *(const short8*)(kp + (size_t)mt * 16 * DD + 32);
        acc[mt] = __builtin_amdgcn_mfma_f32_16x16x32_bf16(a0, b0, acc[mt], 0, 0, 0);
        acc[mt] = __builtin_amdgcn_mfma_f32_16x16x32_bf16(a1, b1, acc[mt], 0, 0, 0);
    }

    float* sp = scores + (size_t)bh * NN * NN;
    #pragma unroll
    for (int mt = 0; mt < 8; ++mt)
        #pragma unroll
        for (int r = 0; r < 4; ++r)
            sp[(size_t)(n0 + lg * 4 + r) * NN + mh * 128 + mt * 16 + lr] = acc[mt][r];
}

// ---------------------------------------------------------------------------
// Kernel 3: fused edges pass (R4 structure restored) + vectorized phase 2.
//   qk preload issued at kernel entry (hides under edges staging).
//   edges loads / edges_out stores nontemporal (single-use streams).
//   Phase 2: thread owns an e-quad -> 8 float4 NT stores instead of 32
//   scalar stores (4x fewer store instrs + address adds).
// grid 8192, 256 threads, LDS ~28.5 KB -> 5 blocks/CU.
// ---------------------------------------------------------------------------
__global__ __launch_bounds__(256) void edges_kernel(
    const float* __restrict__ edges,
    const float* __restrict__ Wa, const float* __restrict__ ba,
    const float* __restrict__ Wg, const float* __restrict__ bg,
    const float* __restrict__ We, const float* __restrict__ be,
    float* __restrict__ scores,
    unsigned short* __restrict__ gates,
    float* __restrict__ edges_out)
{
    __shared__ __align__(16) unsigned short eb[128 * 64];   // 16 KB, swizzled
    __shared__ __align__(16) unsigned short wc[16 * 64];    //  2 KB, WcatT[h'][e]
    __shared__ __align__(16) float bgl[128][20];            // 10 KB, 16B-aligned rows
    __shared__ float bal[8], bgb[8];

    const int mh  = blockIdx.x & 1;
    const int n   = (blockIdx.x >> 1) & 255;
    const int b   = blockIdx.x >> 9;
    const int m0  = mh << 7;
    const int tid = threadIdx.x;
    const int w   = tid >> 6, l = tid & 63;
    const int lr  = l & 15, lg = l >> 4;

    // ---- hoisted fixup-phase loads: issue FIRST, latency hides under staging
    const int fm = tid & 127;                 // fixup m
    const int fh = (tid >> 7) << 2;           // fixup first-h
    const size_t so0 = ((size_t)(b * HH + fh) << 16) + ((size_t)n << 8) + m0 + fm;
    float qk[4];
    #pragma unroll
    for (int i = 0; i < 4; ++i) qk[i] = scores[so0 + ((size_t)i << 16)];

    // phase-2 constants: thread owns e-quad e0 = (l&15)*4, m-offset mo = l>>4
    const int e0 = lr << 2;
    float4 wecol4[8];
    #pragma unroll
    for (int h = 0; h < 8; ++h) wecol4[h] = *(const float4*)(We + h * EE + e0);
    const float4 bev4 = *(const float4*)(be + e0);

    // --- stage edges tile [128][64] fp32 -> bf16 LDS, nontemporal coalesced
    const f32x4* esrc = (const f32x4*)(edges + ((size_t)(b * NN + n) * NN + m0) * DD);
    f32x4 xr[8];
    #pragma unroll
    for (int it = 0; it < 8; ++it)
        xr[it] = __builtin_nontemporal_load(esrc + it * 256 + tid);

    // --- stage WcatT[h'][e] bf16 (h'<8 -> Wa, else Wg), swizzled
    #pragma unroll
    for (int j = 0; j < 4; ++j) {
        const int idx = tid * 4 + j;
        const int hp = idx >> 6, e = idx & 63;
        const float v = (hp < 8) ? Wa[e * 8 + hp] : Wg[e * 8 + (hp - 8)];
        *(unsigned short*)((char*)wc + hp * 128 + ((e * 2) ^ ((hp & 7) << 4))) = f2bf(v);
    }
    if (tid < 8) { bal[tid] = ba[tid]; bgb[tid] = bg[tid]; }

    #pragma unroll
    for (int it = 0; it < 8; ++it) {
        const int c = it * 256 + tid;            // float4 index: m = c>>4, e4 = c&15
        const int m = c >> 4, e4 = c & 15;
        const unsigned lo = (unsigned)f2bf(xr[it][0]) | ((unsigned)f2bf(xr[it][1]) << 16);
        const unsigned hi = (unsigned)f2bf(xr[it][2]) | ((unsigned)f2bf(xr[it][3]) << 16);
        *(uint2*)((char*)eb + m * 128 + ((e4 * 8) ^ ((m & 7) << 4))) = make_uint2(lo, hi);
    }
    __syncthreads();

    // --- B fragments (WcatT rows, conflict-free via swizzle)
    short8 bfrag[2];
    #pragma unroll
    for (int ks = 0; ks < 2; ++ks)
        bfrag[ks] = *(const short8*)((char*)wc + lr * 128 +
                                     ((ks * 64 + lg * 16) ^ ((lr & 7) << 4)));

    // --- MFMA MLP: wave w owns m-tiles {2w, 2w+1}
    #pragma unroll
    for (int t = 0; t < 2; ++t) {
        const int T = w * 2 + t;
        f32x4 acc = (f32x4){0.f, 0.f, 0.f, 0.f};
        #pragma unroll
        for (int ks = 0; ks < 2; ++ks) {
            const int m = T * 16 + lr;
            const short8 af = *(const short8*)((char*)eb + m * 128 +
                                 ((ks * 64 + lg * 16) ^ ((lr & 7) << 4)));
            acc = __builtin_amdgcn_mfma_f32_16x16x32_bf16(af, bfrag[ks], acc, 0, 0, 0);
        }
        // C: col (h') = lr, row (m-in-tile) = lg*4 + r
        #pragma unroll
        for (int r = 0; r < 4; ++r)
            bgl[T * 16 + lg * 4 + r][lr] = acc[r];
    }
    __syncthreads();

    // --- fixup (qk preloaded): coalesced score/gate writes
    #pragma unroll
    for (int i = 0; i < 4; ++i) {
        const int h = fh + i;
        const float sc = qk[i] + bgl[fm][h] + bal[h];
        scores[so0 + ((size_t)i << 16)] = sc;
        bgl[fm][h] = sc;                      // slot owned by this thread
        const float gv = bgl[fm][8 + h] + bgb[h];
        gates[so0 + ((size_t)i << 16)] = f2bf(1.f / (1.f + __expf(-gv)));
    }
    __syncthreads();

    // --- phase 2: edges_out[b, m, n, e0..e0+3] = sum_h sc[m][h]*We[h][e]+be[e]
    //     thread: e-quad e0, m = w*32 + mi*4 + mo  (8 float4 NT stores)
    const int mo = lg;
    #pragma unroll
    for (int mi = 0; mi < 8; ++mi) {
        const int m = w * 32 + mi * 4 + mo;
        const float4 sa = *(const float4*)&bgl[m][0];   // 16-lane broadcast b128
        const float4 sb = *(const float4*)&bgl[m][4];
        f32x4 v = {bev4.x, bev4.y, bev4.z, bev4.w};
        const float sh[8] = {sa.x, sa.y, sa.z, sa.w, sb.x, sb.y, sb.z, sb.w};
        #pragma unroll
        for (int h = 0; h < 8; ++h) {
            v[0] += sh[h] * wecol4[h].x; v[1] += sh[h] * wecol4[h].y;
            v[2] += sh[h] * wecol4[h].z; v[3] += sh[h] * wecol4[h].w;
        }
        __builtin_nontemporal_store(v, (f32x4*)(edges_out +
            ((size_t)(b * NN + m0 + m) * NN + n) * DD + e0));
    }
}

// ---------------------------------------------------------------------------
// Kernel 4: Vgt[b,h,d,n] = (V^T @ g^T) via bf16 MFMA.
// grid 1024 (bh x 4 n-quarters x 2 d-halves), 256 threads, no LDS.
// ---------------------------------------------------------------------------
__global__ __launch_bounds__(256) void vg_kernel(
    const unsigned short* __restrict__ gates, const unsigned short* __restrict__ Vtb,
    unsigned short* __restrict__ Vgt)
{
    const int dh = blockIdx.x & 1;
    const int q  = (blockIdx.x >> 1) & 3;
    const int bh = blockIdx.x >> 3;
    const int tid = threadIdx.x;
    const int w = tid >> 6, l = tid & 63;
    const int lr = l & 15, lg = l >> 4;
    const int n0 = q * 64 + w * 16;

    const unsigned short* gp = gates + ((size_t)bh * NN + n0 + lr) * NN + lg * 8;
    const unsigned short* vp = Vtb + ((size_t)bh * DD + lr) * NN + lg * 8;

    f32x4 acc[2];
    #pragma unroll
    for (int dt = 0; dt < 2; ++dt) acc[dt] = (f32x4){0.f, 0.f, 0.f, 0.f};

    #pragma unroll
    for (int ks = 0; ks < 8; ++ks) {
        const short8 bfr = *(const short8*)(gp + ks * 32);
        #pragma unroll
        for (int dt = 0; dt < 2; ++dt) {
            const short8 afr = *(const short8*)(vp + (size_t)(dh * 2 + dt) * 16 * NN + ks * 32);
            acc[dt] = __builtin_amdgcn_mfma_f32_16x16x32_bf16(afr, bfr, acc[dt], 0, 0, 0);
        }
    }

    unsigned short* op = Vgt + (size_t)bh * DD * NN;
    #pragma unroll
    for (int dt = 0; dt < 2; ++dt)
        #pragma unroll
        for (int r = 0; r < 4; ++r)
            op[(size_t)((dh * 2 + dt) * 16 + lg * 4 + r) * NN + n0 + lr] = f2bf(acc[dt][r]);
}

// ---------------------------------------------------------------------------
// Kernel 5: softmax(scores) @ Vg + projection. 512 threads, wave = head.
// grid 256 (b x 16 n-tiles), LDS 33.3 KB. NT scores reads (last consumer).
// ---------------------------------------------------------------------------
__global__ __launch_bounds__(512) void out_kernel(
    const float* __restrict__ scores, const unsigned short* __restrict__ Vgt,
    const float* __restrict__ Wo, const float* __restrict__ bo,
    float* __restrict__ att_out)
{
    __shared__ float o_l[16][521];
    const int b  = blockIdx.x >> 4;
    const int nt = blockIdx.x & 15;
    const int n0 = nt * 16;
    const int tid = threadIdx.x;
    const int w = tid >> 6, l = tid & 63;
    const int lr = l & 15, lg = l >> 4;
    const int h = w;                          // one head per wave

    {
        const f32x4* sp = (const f32x4*)(scores +
            ((size_t)(b * HH + h) * NN + n0 + lr) * NN + lg * 8);
        float s[64];
        #pragma unroll
        for (int ks = 0; ks < 8; ++ks) {
            const f32x4 x0 = __builtin_nontemporal_load(sp + ks * 8);
            const f32x4 x1 = __builtin_nontemporal_load(sp + ks * 8 + 1);
            s[ks * 8 + 0] = x0[0]; s[ks * 8 + 1] = x0[1];
            s[ks * 8 + 2] = x0[2]; s[ks * 8 + 3] = x0[3];
            s[ks * 8 + 4] = x1[0]; s[ks * 8 + 5] = x1[1];
            s[ks * 8 + 6] = x1[2]; s[ks * 8 + 7] = x1[3];
        }
        float mx = -1e30f;
        #pragma unroll
        for (int i = 0; i < 64; ++i) mx = fmaxf(mx, s[i]);
        mx = fmaxf(mx, __shfl_xor(mx, 16, 64));
        mx = fmaxf(mx, __shfl_xor(mx, 32, 64));
        float sm = 0.f;
        #pragma unroll
        for (int i = 0; i < 64; ++i) { s[i] = __expf(s[i] - mx); sm += s[i]; }
        sm += __shfl_xor(sm, 16, 64);
        sm += __shfl_xor(sm, 32, 64);
        const float inv = 1.f / sm;

        const unsigned short* vp = Vgt + ((size_t)(b * HH + h) * DD + lr) * NN + lg * 8;
        f32x4 acc[4];
        #pragma unroll
        for (int dt = 0; dt < 4; ++dt) acc[dt] = (f32x4){0.f, 0.f, 0.f, 0.f};

        #pragma unroll
        for (int ks = 0; ks < 8; ++ks) {
            union { short8 v; unsigned short u[8]; } bf;
            #pragma unroll
            for (int j = 0; j < 8; ++j) bf.u[j] = f2bf(s[ks * 8 + j] * inv);
            #pragma unroll
            for (int dt = 0; dt < 4; ++dt) {
                const short8 afr = *(const short8*)(vp + (size_t)dt * 16 * NN + ks * 32);
                acc[dt] = __builtin_amdgcn_mfma_f32_16x16x32_bf16(afr, bf.v, acc[dt], 0, 0, 0);
            }
        }
        // C: row = d' = dt*16+lg*4+r, col = n' = lr
        #pragma unroll
        for (int dt = 0; dt < 4; ++dt)
            #pragma unroll
            for (int r = 0; r < 4; ++r)
                o_l[lr][h * 64 + dt * 16 + lg * 4 + r] = acc[dt][r];
    }
    __syncthreads();

    // projection: thread (n = tid>>5, d-pair = (tid&31)*2); Wo coalesced
    const int n  = tid >> 5;
    const int d2 = (tid & 31) << 1;
    float a0 = bo[d2], a1 = bo[d2 + 1];
    const float* orow = &o_l[n][0];
    #pragma unroll 8
    for (int k = 0; k < 512; ++k) {
        const float o = orow[k];
        const float2 w2 = *(const float2*)(Wo + (size_t)k * 64 + d2);
        a0 += o * w2.x; a1 += o * w2.y;
    }
    *(float2*)(att_out + ((size_t)(b * NN + n0 + n)) * DD + d2) = make_float2(a0, a1);
}

extern "C" void kernel_launch(void* const* d_in, const int* in_sizes, int n_in,
                              void* d_out, int out_size, void* d_ws, size_t ws_size,
                              hipStream_t stream)
{
    const float* query = (const float*)d_in[0];
    const float* edges = (const float*)d_in[1];
    const float* Wq = (const float*)d_in[2];  const float* bq = (const float*)d_in[3];
    const float* Wk = (const float*)d_in[4];  const float* bk = (const float*)d_in[5];
    const float* Wv = (const float*)d_in[6];  const float* bv = (const float*)d_in[7];
    const float* Wa = (const float*)d_in[8];  const float* ba = (const float*)d_in[9];
    const float* Wg = (const float*)d_in[10]; const float* bg = (const float*)d_in[11];
    const float* Wo = (const float*)d_in[12]; const float* bo = (const float*)d_in[13];
    const float* We = (const float*)d_in[14]; const float* be = (const float*)d_in[15];

    float* att_out   = (float*)d_out;
    float* edges_out = (float*)d_out + 262144;  // B*N*D

    char* base = (char*)d_ws;
    float*          scores = (float*)base;                          // 33,554,432 B
    unsigned short* gates  = (unsigned short*)(base + 33554432);    // 16,777,216 B
    unsigned short* Qb     = (unsigned short*)(base + 50331648);    //  4,194,304 B
    unsigned short* Kb     = (unsigned short*)(base + 54525952);    //  4,194,304 B
    unsigned short* Vtb    = (unsigned short*)(base + 58720256);    //  4,194,304 B
    unsigned short* Vgt    = (unsigned short*)(base + 62914560);    //  4,194,304 B

    hipLaunchKernelGGL(qkv_kernel, dim3(1536), dim3(256), 0, stream,
                       query, Wq, bq, Wk, bk, Wv, bv, Qb, Kb, Vtb);
    hipLaunchKernelGGL(qk_kernel, dim3(1024), dim3(256), 0, stream,
                       Qb, Kb, scores);
    hipLaunchKernelGGL(edges_kernel, dim3(8192), dim3(256), 0, stream,
                       edges, Wa, ba, Wg, bg, We, be, scores, gates, edges_out);
    hipLaunchKernelGGL(vg_kernel, dim3(1024), dim3(256), 0, stream,
                       gates, Vtb, Vgt);
    hipLaunchKernelGGL(out_kernel, dim3(256), dim3(512), 0, stream,
                       scores, Vgt, Wo, bo, att_out);
}